// Round 1
// baseline (11411.169 us; speedup 1.0000x reference)
//
#include <hip/hip_runtime.h>
#include <math.h>

// Problem constants (match reference)
#define Bv   1024
#define Kv   20
#define DNv  172
#define DEv  172
#define DTv  100
#define QDv  272      // DN + DT
#define KDv  444      // DN + DE + DT
#define HDv  136      // QD / NH
#define NHv  2
#define NT   320      // 5 waves; threads 0..271 own one output column each

// Fused temporal-graph-attention layer.
// LAYER==0: conv features are gathered (memories+node_raw); writes layer-1 outputs to ws.
// LAYER==1: conv features come from ws (node_conv / nbr_conv); writes final output.
template <int LAYER>
__global__ __launch_bounds__(NT, 2)
void tgat_layer(const float* __restrict__ node_raw, const float* __restrict__ edge_raw,
                const float* __restrict__ memories,
                const float* __restrict__ t_node, const float* __restrict__ t_n1,
                const float* __restrict__ t_n2,
                const float* __restrict__ time_w, const float* __restrict__ time_b,
                const float* __restrict__ Wq, const float* __restrict__ Wk,
                const float* __restrict__ Wv, const float* __restrict__ Wo,
                const float* __restrict__ bo,
                const float* __restrict__ ln_g, const float* __restrict__ ln_b,
                const float* __restrict__ w1, const float* __restrict__ b1,
                const float* __restrict__ w2, const float* __restrict__ b2,
                const int* __restrict__ node_ids, const int* __restrict__ n1_ids,
                const int* __restrict__ n1_eids, const int* __restrict__ n2_ids,
                const int* __restrict__ n2_eids,
                const float* __restrict__ conv_q,   // LAYER==1: node_conv [B][DN]
                const float* __restrict__ conv_kv,  // LAYER==1: nbr_conv [B*K][DN]
                float* __restrict__ out_a,          // LAYER==0: node_conv ws; LAYER==1: d_out
                float* __restrict__ out_b)          // LAYER==0: nbr_conv ws
{
  __shared__ __align__(16) float s_kv[Kv * KDv];   // 35.5 KB: kv_in tile
  __shared__ __align__(16) float s_k[Kv * QDv];    // 21.8 KB: K projections
  __shared__ float s_qin[QDv];                     // q_in (also residual)
  __shared__ float s_q[QDv];                       // q projection, reused for attn-out
  __shared__ float s_x[QDv];                       // post-residual / post-LN
  __shared__ float s_nf[DNv];                      // merge residual input x2
  __shared__ float s_h[DNv];                       // merge hidden
  __shared__ float s_sc[NHv * Kv];
  __shared__ float s_att[NHv * Kv];
  __shared__ int   s_nid[Kv];
  __shared__ float s_td[Kv];
  __shared__ float s_ws[5], s_wq[5];
  __shared__ float s_mu, s_rs;

  const int m   = blockIdx.x;
  const int tid = threadIdx.x;

  int qid; float qt;
  const int* nbI; const int* nbE; const float* nbT;
  if (LAYER == 0) {
    if (m < Bv) {
      qid = node_ids[m]; qt = t_node[m];
      nbI = n1_ids + (size_t)m * Kv; nbE = n1_eids + (size_t)m * Kv; nbT = t_n1 + (size_t)m * Kv;
    } else {
      const int mm = m - Bv;
      qid = n1_ids[mm]; qt = t_n1[mm];
      nbI = n2_ids + (size_t)mm * Kv; nbE = n2_eids + (size_t)mm * Kv; nbT = t_n2 + (size_t)mm * Kv;
    }
  } else {
    qid = node_ids[m]; qt = t_node[m];
    nbI = n1_ids + (size_t)m * Kv; nbE = n1_eids + (size_t)m * Kv; nbT = t_n1 + (size_t)m * Kv;
  }

  if (tid < Kv) { s_nid[tid] = nbI[tid]; s_td[tid] = qt - nbT[tid]; }

  // ---- stage q_in (conv || time-encode(0)) and merge residual nf ----
  for (int j = tid; j < QDv; j += NT) {
    float v;
    if (j < DNv)
      v = (LAYER == 0) ? (memories[(size_t)qid * DNv + j] + node_raw[(size_t)qid * DNv + j])
                       : conv_q[(size_t)m * DNv + j];
    else
      v = cosf(time_b[j - DNv]);            // t = 0 -> cos(b)
    s_qin[j] = v;
  }
  for (int j = tid; j < DNv; j += NT)
    s_nf[j] = memories[(size_t)qid * DNv + j] + node_raw[(size_t)qid * DNv + j];
  __syncthreads();   // s_nid/s_td visible for kv staging

  // ---- stage kv_in = [nbr_conv | edge_feat | time_feat] : (K, 444) ----
  for (int idx = tid; idx < Kv * KDv; idx += NT) {
    const int i = idx / KDv;
    const int c = idx - i * KDv;
    float v;
    if (c < DNv) {
      const int nid = s_nid[i];
      v = (LAYER == 0) ? (memories[(size_t)nid * DNv + c] + node_raw[(size_t)nid * DNv + c])
                       : conv_kv[((size_t)m * Kv + i) * DNv + c];
    } else if (c < DNv + DEv) {
      v = edge_raw[(size_t)nbE[i] * DEv + (c - DNv)];
    } else {
      const int j = c - (DNv + DEv);
      v = cosf(s_td[i] * time_w[j] + time_b[j]);
    }
    s_kv[idx] = v;
  }
  __syncthreads();

  // ---- q = q_in @ Wq (272x272 matvec) ----
  if (tid < QDv) {
    float acc = 0.f;
    for (int c = 0; c < QDv; ++c) acc = fmaf(s_qin[c], Wq[c * QDv + tid], acc);
    s_q[tid] = acc;
  }

  // ---- K,V projections: thread j owns column j; V stays in registers ----
  float av[Kv];
  if (tid < QDv) {
    const int j = tid;
    float ak[Kv];
    #pragma unroll
    for (int i = 0; i < Kv; ++i) { ak[i] = 0.f; av[i] = 0.f; }
    for (int c = 0; c < KDv; c += 4) {
      const float wk0 = Wk[(c + 0) * QDv + j], wk1 = Wk[(c + 1) * QDv + j];
      const float wk2 = Wk[(c + 2) * QDv + j], wk3 = Wk[(c + 3) * QDv + j];
      const float wv0 = Wv[(c + 0) * QDv + j], wv1 = Wv[(c + 1) * QDv + j];
      const float wv2 = Wv[(c + 2) * QDv + j], wv3 = Wv[(c + 3) * QDv + j];
      #pragma unroll
      for (int i = 0; i < Kv; ++i) {
        const float4 a = *(const float4*)&s_kv[i * KDv + c];
        ak[i] = fmaf(a.x, wk0, fmaf(a.y, wk1, fmaf(a.z, wk2, fmaf(a.w, wk3, ak[i]))));
        av[i] = fmaf(a.x, wv0, fmaf(a.y, wv1, fmaf(a.z, wv2, fmaf(a.w, wv3, av[i]))));
      }
    }
    #pragma unroll
    for (int i = 0; i < Kv; ++i) s_k[i * QDv + j] = ak[i];
  }
  __syncthreads();

  // ---- scores: 40 groups of 8 lanes, each a 136-elem dot q.k ----
  {
    const int g = tid >> 3;            // 0..39 == h*20+i
    const int l = tid & 7;
    const int h = g / Kv;
    const int i = g - h * Kv;
    float p = 0.f;
    for (int d = l; d < HDv; d += 8)
      p = fmaf(s_q[h * HDv + d], s_k[i * QDv + h * HDv + d], p);
    p += __shfl_xor(p, 1); p += __shfl_xor(p, 2); p += __shfl_xor(p, 4);
    if (l == 0) {
      p *= 0.08574929257125442f;       // 136^-0.5
      if (s_nid[i] == 0) p = -1e10f;   // mask padded neighbors
      s_sc[g] = p;
    }
  }
  __syncthreads();

  // ---- softmax over K per head (2 serial threads; 20 elems each) ----
  if (tid < NHv) {
    float mx = -INFINITY;
    for (int i = 0; i < Kv; ++i) mx = fmaxf(mx, s_sc[tid * Kv + i]);
    float e[Kv]; float sum = 0.f;
    for (int i = 0; i < Kv; ++i) { e[i] = expf(s_sc[tid * Kv + i] - mx); sum += e[i]; }
    const float inv = 1.f / sum;
    for (int i = 0; i < Kv; ++i) s_att[tid * Kv + i] = e[i] * inv;
  }
  __syncthreads();

  // ---- attn out from V registers; reuse s_q ----
  if (tid < QDv) {
    const int h = tid / HDv;
    float o = 0.f;
    #pragma unroll
    for (int i = 0; i < Kv; ++i) o = fmaf(s_att[h * Kv + i], av[i], o);
    s_q[tid] = o;
  }
  __syncthreads();

  // ---- x = out @ Wo + bo + q_in ----
  if (tid < QDv) {
    float acc = bo[tid] + s_qin[tid];
    for (int c = 0; c < QDv; ++c) acc = fmaf(s_q[c], Wo[c * QDv + tid], acc);
    s_x[tid] = acc;
  }
  __syncthreads();

  // ---- LayerNorm(272) ----
  {
    float vs = 0.f, vq = 0.f;
    if (tid < QDv) { const float xv = s_x[tid]; vs = xv; vq = xv * xv; }
    for (int off = 1; off < 64; off <<= 1) { vs += __shfl_xor(vs, off); vq += __shfl_xor(vq, off); }
    if ((tid & 63) == 0) { s_ws[tid >> 6] = vs; s_wq[tid >> 6] = vq; }
    __syncthreads();
    if (tid == 0) {
      float a = 0.f, b = 0.f;
      for (int w = 0; w < 5; ++w) { a += s_ws[w]; b += s_wq[w]; }
      const float mu = a / (float)QDv;
      const float var = b / (float)QDv - mu * mu;
      s_mu = mu; s_rs = 1.0f / sqrtf(var + 1e-5f);
    }
    __syncthreads();
    if (tid < QDv)
      s_x[tid] = (s_x[tid] - s_mu) * s_rs * ln_g[tid] + ln_b[tid];
    __syncthreads();
  }

  // ---- merge: h = relu(cat(x, nf) @ w1 + b1) ----
  if (tid < DNv) {
    float acc = b1[tid];
    for (int c = 0; c < QDv; ++c) acc = fmaf(s_x[c], w1[c * DNv + tid], acc);
    for (int c = 0; c < DNv; ++c) acc = fmaf(s_nf[c], w1[(QDv + c) * DNv + tid], acc);
    s_h[tid] = fmaxf(acc, 0.f);
  }
  __syncthreads();

  // ---- out = h @ w2 + b2 ----
  if (tid < DNv) {
    float acc = b2[tid];
    for (int c = 0; c < DNv; ++c) acc = fmaf(s_h[c], w2[c * DNv + tid], acc);
    float* dst;
    if (LAYER == 0) dst = (m < Bv) ? (out_a + (size_t)m * DNv) : (out_b + (size_t)(m - Bv) * DNv);
    else            dst = out_a + (size_t)m * DNv;
    dst[tid] = acc;
  }
}

extern "C" void kernel_launch(void* const* d_in, const int* in_sizes, int n_in,
                              void* d_out, int out_size, void* d_ws, size_t ws_size,
                              hipStream_t stream) {
  (void)in_sizes; (void)n_in; (void)out_size; (void)ws_size;
  const float* node_raw = (const float*)d_in[0];
  const float* edge_raw = (const float*)d_in[1];
  const float* memories = (const float*)d_in[2];
  const float* t_node   = (const float*)d_in[3];
  const float* t_n1     = (const float*)d_in[4];
  const float* t_n2     = (const float*)d_in[5];
  const float* time_w   = (const float*)d_in[6];
  const float* time_b   = (const float*)d_in[7];
  const float* Wq       = (const float*)d_in[8];
  const float* Wk       = (const float*)d_in[9];
  const float* Wv       = (const float*)d_in[10];
  const float* Wo       = (const float*)d_in[11];
  const float* bo       = (const float*)d_in[12];
  const float* ln_g     = (const float*)d_in[13];
  const float* ln_b     = (const float*)d_in[14];
  const float* m_w1     = (const float*)d_in[15];
  const float* m_b1     = (const float*)d_in[16];
  const float* m_w2     = (const float*)d_in[17];
  const float* m_b2     = (const float*)d_in[18];
  const int* node_ids   = (const int*)d_in[19];
  const int* n1_ids     = (const int*)d_in[20];
  const int* n1_eids    = (const int*)d_in[21];
  const int* n2_ids     = (const int*)d_in[22];
  const int* n2_eids    = (const int*)d_in[23];

  // workspace: node_conv (B x DN) then nbr_conv (B*K x DN)  => ~14.8 MB
  float* node_conv = (float*)d_ws;
  float* nbr_conv  = node_conv + (size_t)Bv * DNv;

  // layer 1 over combined row set: [0,B) = node set, [B, B+B*K) = neighbor set
  tgat_layer<0><<<dim3(Bv + Bv * Kv), dim3(NT), 0, stream>>>(
      node_raw, edge_raw, memories, t_node, t_n1, t_n2, time_w, time_b,
      Wq, Wk, Wv, Wo, bo, ln_g, ln_b,
      m_w1, m_b1, m_w2, m_b2,
      node_ids, n1_ids, n1_eids, n2_ids, n2_eids,
      nullptr, nullptr, node_conv, nbr_conv);

  // layer 2 (weight slice [1])
  tgat_layer<1><<<dim3(Bv), dim3(NT), 0, stream>>>(
      node_raw, edge_raw, memories, t_node, t_n1, t_n2, time_w, time_b,
      Wq + QDv * QDv, Wk + KDv * QDv, Wv + KDv * QDv, Wo + QDv * QDv, bo + QDv,
      ln_g + QDv, ln_b + QDv,
      m_w1 + (QDv + DNv) * DNv, m_b1 + DNv, m_w2 + DNv * DNv, m_b2 + DNv,
      node_ids, n1_ids, n1_eids, n2_ids, n2_eids,
      node_conv, nbr_conv, (float*)d_out, nullptr);
}

// Round 3
// 2685.782 us; speedup vs baseline: 4.2487x; 4.2487x over previous
//
#include <hip/hip_runtime.h>
#include <math.h>

// ---------------- problem constants ----------------
#define Bq    1024
#define Kn    20
#define DN    172
#define DT    100
#define QD    272            // DN + DT
#define KD    444            // DN + DE + DT
#define HD    136            // QD / 2 heads
#define M0    21504          // Bq + Bq*Kn  (layer-1 row count)

// ---------------- prep: transpose Wk (both layers) ----------------
__global__ __launch_bounds__(256)
void prep_wkt(const float* __restrict__ Wk, float* __restrict__ wkT) {
  const int idx = blockIdx.x * 256 + threadIdx.x;
  const int tot = 2 * QD * KD;
  if (idx >= tot) return;
  const int l = idx / (QD * KD);
  const int rem = idx - l * QD * KD;
  const int j = rem / KD, c = rem - j * KD;
  // wkT[l][j][c] = Wk[l][c][j]
  wkT[(size_t)l * QD * KD + (size_t)j * KD + c] =
      Wk[(size_t)l * KD * QD + (size_t)c * QD + j];
}

// ---------------- build Q_in = [conv | cos(time_b)] ----------------
template <int LAYER>
__global__ __launch_bounds__(320)
void build_qin(const float* __restrict__ memories, const float* __restrict__ node_raw,
               const float* __restrict__ conv1, const float* __restrict__ time_b,
               const int* __restrict__ node_ids, const int* __restrict__ n1_ids,
               int chunk_off, float* __restrict__ qin) {
  const int r = blockIdx.x, tid = threadIdx.x;
  const int g = chunk_off + r;
  if (tid >= QD) return;
  float v;
  if (tid < DN) {
    if (LAYER == 0) {
      const int id = (g < Bq) ? node_ids[g] : n1_ids[g - Bq];
      v = memories[(size_t)id * DN + tid] + node_raw[(size_t)id * DN + tid];
    } else {
      v = conv1[(size_t)g * DN + tid];
    }
  } else {
    v = cosf(time_b[tid - DN]);     // t = 0
  }
  qin[(size_t)r * QD + tid] = v;
}

// ---------------- generic fp32 GEMM: C = act(A@B + bias + res) ----------------
// BM=BN=64, BK=16, 256 threads, 4x4 micro-tile. M must be a multiple of 64.
template <bool BIAS, bool RES, bool RELU>
__global__ __launch_bounds__(256)
void gemm_k(const float* __restrict__ A, int lda,
            const float* __restrict__ B, int ldb,
            float* __restrict__ C, int ldc,
            const float* __restrict__ bias,
            const float* __restrict__ res, int ldr,
            int N, int K) {
  __shared__ __align__(16) float As[16][68];  // [k][m], 68: float4-aligned rows
  __shared__ __align__(16) float Bs[16][68];  // [k][n]
  const int tid = threadIdx.x;
  const int bm = blockIdx.x * 64;
  const int bn = blockIdx.y * 64;
  const int r0 = (tid >> 4) << 2;
  const int c0 = (tid & 15) << 2;
  const int arow = tid >> 2;
  const int ak0  = (tid & 3) << 2;
  const int bkr  = tid >> 4;
  const int bn0  = (tid & 15) << 2;
  float acc[4][4] = {{0.f, 0.f, 0.f, 0.f}, {0.f, 0.f, 0.f, 0.f},
                     {0.f, 0.f, 0.f, 0.f}, {0.f, 0.f, 0.f, 0.f}};
  const float* Aptr = A + (size_t)(bm + arow) * lda;
  const int nkb = (K + 15) >> 4;
  for (int kb = 0; kb < nkb; ++kb) {
    const int kA = (kb << 4) + ak0;
    float4 av;
    if (kA + 3 < K) {
      av = *(const float4*)(Aptr + kA);
    } else {
      av.x = (kA + 0 < K) ? Aptr[kA + 0] : 0.f;
      av.y = (kA + 1 < K) ? Aptr[kA + 1] : 0.f;
      av.z = (kA + 2 < K) ? Aptr[kA + 2] : 0.f;
      av.w = (kA + 3 < K) ? Aptr[kA + 3] : 0.f;
    }
    As[ak0 + 0][arow] = av.x;
    As[ak0 + 1][arow] = av.y;
    As[ak0 + 2][arow] = av.z;
    As[ak0 + 3][arow] = av.w;

    const int kB = (kb << 4) + bkr;
    float4 bv = make_float4(0.f, 0.f, 0.f, 0.f);
    if (kB < K) {
      const float* Bp = B + (size_t)kB * ldb + bn + bn0;
      if (bn + bn0 + 3 < N) {
        bv = *(const float4*)Bp;
      } else {
        if (bn + bn0 + 0 < N) bv.x = Bp[0];
        if (bn + bn0 + 1 < N) bv.y = Bp[1];
        if (bn + bn0 + 2 < N) bv.z = Bp[2];
        if (bn + bn0 + 3 < N) bv.w = Bp[3];
      }
    }
    *(float4*)&Bs[bkr][bn0] = bv;
    __syncthreads();
    #pragma unroll
    for (int k = 0; k < 16; ++k) {
      const float4 a = *(const float4*)&As[k][r0];
      const float4 b = *(const float4*)&Bs[k][c0];
      acc[0][0] = fmaf(a.x, b.x, acc[0][0]);
      acc[0][1] = fmaf(a.x, b.y, acc[0][1]);
      acc[0][2] = fmaf(a.x, b.z, acc[0][2]);
      acc[0][3] = fmaf(a.x, b.w, acc[0][3]);
      acc[1][0] = fmaf(a.y, b.x, acc[1][0]);
      acc[1][1] = fmaf(a.y, b.y, acc[1][1]);
      acc[1][2] = fmaf(a.y, b.z, acc[1][2]);
      acc[1][3] = fmaf(a.y, b.w, acc[1][3]);
      acc[2][0] = fmaf(a.z, b.x, acc[2][0]);
      acc[2][1] = fmaf(a.z, b.y, acc[2][1]);
      acc[2][2] = fmaf(a.z, b.z, acc[2][2]);
      acc[2][3] = fmaf(a.z, b.w, acc[2][3]);
      acc[3][0] = fmaf(a.w, b.x, acc[3][0]);
      acc[3][1] = fmaf(a.w, b.y, acc[3][1]);
      acc[3][2] = fmaf(a.w, b.z, acc[3][2]);
      acc[3][3] = fmaf(a.w, b.w, acc[3][3]);
    }
    __syncthreads();
  }
  #pragma unroll
  for (int i = 0; i < 4; ++i) {
    const int row = bm + r0 + i;
    #pragma unroll
    for (int j = 0; j < 4; ++j) {
      const int col = bn + c0 + j;
      if (col < N) {
        float v = acc[i][j];
        if (BIAS) v += bias[col];
        if (RES)  v += res[(size_t)row * ldr + col];
        if (RELU) v = fmaxf(v, 0.f);
        C[(size_t)row * ldc + col] = v;
      }
    }
  }
}

// ---------------- attention core: s = kv@t, softmax, z = att^T@kv ----------------
template <int LAYER>
__global__ __launch_bounds__(320)
void attn_core(const float* __restrict__ memories, const float* __restrict__ node_raw,
               const float* __restrict__ edge_raw, const float* __restrict__ conv1,
               const float* __restrict__ t_node, const float* __restrict__ t_n1,
               const float* __restrict__ t_n2,
               const float* __restrict__ time_w, const float* __restrict__ time_b,
               const int* __restrict__ n1_ids, const int* __restrict__ n1_eids,
               const int* __restrict__ n2_ids, const int* __restrict__ n2_eids,
               int chunk_off, float* __restrict__ T) {
  __shared__ float s_kv[Kn][KD];      // 35.5 KB
  __shared__ float s_t[2 * KD];       // 3.5 KB
  __shared__ float s_sc[40];          // [h*20+i]
  __shared__ float s_att[40];
  __shared__ int   s_nid[Kn];
  __shared__ int   s_eid[Kn];
  __shared__ float s_td[Kn];
  const int m = blockIdx.x, tid = threadIdx.x;
  const int g = chunk_off + m;

  if (tid < Kn) {
    int nid, eid; float td;
    if (LAYER == 0) {
      if (g < Bq) {
        nid = n1_ids[(size_t)g * Kn + tid];
        eid = n1_eids[(size_t)g * Kn + tid];
        td = t_node[g] - t_n1[(size_t)g * Kn + tid];
      } else {
        const int gg = g - Bq;
        nid = n2_ids[(size_t)gg * Kn + tid];
        eid = n2_eids[(size_t)gg * Kn + tid];
        td = t_n1[gg] - t_n2[(size_t)gg * Kn + tid];
      }
    } else {
      nid = n1_ids[(size_t)g * Kn + tid];
      eid = n1_eids[(size_t)g * Kn + tid];
      td = t_node[g] - t_n1[(size_t)g * Kn + tid];
    }
    s_nid[tid] = nid; s_eid[tid] = eid; s_td[tid] = td;
  }
  for (int j = tid; j < 2 * KD; j += 320) s_t[j] = T[(size_t)m * 2 * KD + j];
  __syncthreads();

  // stage kv_in = [conv | edge | time] (20 x 444)
  for (int idx = tid; idx < Kn * KD; idx += 320) {
    const int i = idx / KD, c = idx - i * KD;
    float v;
    if (c < DN) {
      if (LAYER == 0) {
        const int nid = s_nid[i];
        v = memories[(size_t)nid * DN + c] + node_raw[(size_t)nid * DN + c];
      } else {
        v = conv1[(size_t)(Bq + g * Kn + i) * DN + c];
      }
    } else if (c < 2 * DN) {
      v = edge_raw[(size_t)s_eid[i] * DN + (c - DN)];
    } else {
      const int j = c - 2 * DN;
      v = cosf(fmaf(s_td[i], time_w[j], time_b[j]));
    }
    s_kv[i][c] = v;
  }
  __syncthreads();

  // scores: 40 (i,h) pairs x 8 lanes, dot length 444
  {
    const int p = tid >> 3, l = tid & 7;    // p in [0,40)
    const int h = p / Kn, i = p - h * Kn;
    float s = 0.f;
    for (int c = l; c < KD; c += 8) s = fmaf(s_kv[i][c], s_t[h * KD + c], s);
    s += __shfl_xor(s, 1); s += __shfl_xor(s, 2); s += __shfl_xor(s, 4);
    if (l == 0) {
      s *= 0.08574929257125442f;            // 136^-0.5
      if (s_nid[i] == 0) s = -1e10f;
      s_sc[p] = s;
    }
  }
  __syncthreads();

  if (tid < 2) {
    float mx = -INFINITY;
    for (int i = 0; i < Kn; ++i) mx = fmaxf(mx, s_sc[tid * Kn + i]);
    float e[Kn], sum = 0.f;
    for (int i = 0; i < Kn; ++i) { e[i] = expf(s_sc[tid * Kn + i] - mx); sum += e[i]; }
    const float inv = 1.f / sum;
    for (int i = 0; i < Kn; ++i) s_att[tid * Kn + i] = e[i] * inv;
  }
  __syncthreads();

  // z[h][c] = sum_i att[h][i] * kv[i][c]  -> overwrite T row (in-place)
  for (int o = tid; o < 2 * KD; o += 320) {
    const int h = o / KD, c = o - h * KD;
    float z = 0.f;
    #pragma unroll
    for (int i = 0; i < Kn; ++i) z = fmaf(s_att[h * Kn + i], s_kv[i][c], z);
    T[(size_t)m * 2 * KD + o] = z;
  }
}

// ---------------- LayerNorm + build cat(x, nf) ----------------
template <int LAYER>
__global__ __launch_bounds__(320)
void ln_cat(const float* __restrict__ x,
            const float* __restrict__ ln_g, const float* __restrict__ ln_b,
            const float* __restrict__ memories, const float* __restrict__ node_raw,
            const int* __restrict__ node_ids, const int* __restrict__ n1_ids,
            int chunk_off, float* __restrict__ cat) {
  __shared__ float s_ws[5], s_wq[5];
  __shared__ float s_mu, s_rs;
  const int r = blockIdx.x, tid = threadIdx.x;
  const int g = chunk_off + r;
  float xv = 0.f;
  if (tid < QD) xv = x[(size_t)r * QD + tid];
  float vs = (tid < QD) ? xv : 0.f;
  float vq = (tid < QD) ? xv * xv : 0.f;
  for (int off = 1; off < 64; off <<= 1) {
    vs += __shfl_xor(vs, off);
    vq += __shfl_xor(vq, off);
  }
  if ((tid & 63) == 0) { s_ws[tid >> 6] = vs; s_wq[tid >> 6] = vq; }
  __syncthreads();
  if (tid == 0) {
    float a = 0.f, b = 0.f;
    for (int w = 0; w < 5; ++w) { a += s_ws[w]; b += s_wq[w]; }
    const float mu = a / (float)QD;
    const float var = b / (float)QD - mu * mu;
    s_mu = mu; s_rs = 1.0f / sqrtf(var + 1e-5f);
  }
  __syncthreads();
  if (tid < QD)
    cat[(size_t)r * (QD + DN) + tid] = (xv - s_mu) * s_rs * ln_g[tid] + ln_b[tid];
  if (tid < DN) {
    int id;
    if (LAYER == 0) id = (g < Bq) ? node_ids[g] : n1_ids[g - Bq];
    else            id = node_ids[g];
    cat[(size_t)r * (QD + DN) + QD + tid] =
        memories[(size_t)id * DN + tid] + node_raw[(size_t)id * DN + tid];
  }
}

// ---------------- launcher ----------------
static inline dim3 ggrid(int M, int N) { return dim3(M / 64, (N + 63) / 64); }

extern "C" void kernel_launch(void* const* d_in, const int* in_sizes, int n_in,
                              void* d_out, int out_size, void* d_ws, size_t ws_size,
                              hipStream_t stream) {
  (void)in_sizes; (void)n_in; (void)out_size;
  const float* node_raw = (const float*)d_in[0];
  const float* edge_raw = (const float*)d_in[1];
  const float* memories = (const float*)d_in[2];
  const float* t_node   = (const float*)d_in[3];
  const float* t_n1     = (const float*)d_in[4];
  const float* t_n2     = (const float*)d_in[5];
  const float* time_w   = (const float*)d_in[6];
  const float* time_b   = (const float*)d_in[7];
  const float* Wq       = (const float*)d_in[8];
  const float* Wk       = (const float*)d_in[9];
  const float* Wv       = (const float*)d_in[10];
  const float* Wo       = (const float*)d_in[11];
  const float* bo       = (const float*)d_in[12];
  const float* ln_g     = (const float*)d_in[13];
  const float* ln_b     = (const float*)d_in[14];
  const float* m_w1     = (const float*)d_in[15];
  const float* m_b1     = (const float*)d_in[16];
  const float* m_w2     = (const float*)d_in[17];
  const float* m_b2     = (const float*)d_in[18];
  const int* node_ids   = (const int*)d_in[19];
  const int* n1_ids     = (const int*)d_in[20];
  const int* n1_eids    = (const int*)d_in[21];
  const int* n2_ids     = (const int*)d_in[22];
  const int* n2_eids    = (const int*)d_in[23];

  // ---- runtime workspace layout (deterministic in ws_size -> graph-safe) ----
  // fixed: wkT (2*QD*KD = 241536) + conv1 (M0*DN = 3698688)
  // per-chunk: qin MC*QD + q MC*QD + t MC*2*KD  (cat MC*444 and h MC*172 alias
  // inside the t region: 444 + 172 = 616 <= 888)
  const size_t fixed = (size_t)2 * QD * KD + (size_t)M0 * DN;
  int MC = 1344;                                   // minimum footprint ~23.5 MB
  const size_t per_row = 2 * QD + 2 * KD;          // 1432 floats
  if ((fixed + (size_t)5376 * per_row) * 4 <= ws_size)      MC = 5376;
  else if ((fixed + (size_t)2688 * per_row) * 4 <= ws_size) MC = 2688;
  const int nchunk = M0 / MC;

  float* ws    = (float*)d_ws;
  float* wkT   = ws;
  float* conv1 = ws + (size_t)2 * QD * KD;
  float* qin   = ws + fixed;
  float* q     = qin + (size_t)MC * QD;   // q proj; later attention output
  float* t     = q   + (size_t)MC * QD;   // t; z in-place; later cat+h
  float* cat   = t;                       // MC x 444
  float* h     = t + (size_t)MC * (QD + DN);  // MC x 172, disjoint from cat

  prep_wkt<<<(2 * QD * KD + 255) / 256, 256, 0, stream>>>(Wk, wkT);

  // ---------- layer 1 (rows: 1024 node queries + 20480 neighbor queries) ----------
  for (int ch = 0; ch < nchunk; ++ch) {
    const int off = ch * MC;
    build_qin<0><<<MC, 320, 0, stream>>>(memories, node_raw, nullptr, time_b,
                                         node_ids, n1_ids, off, qin);
    // q = qin @ Wq0
    gemm_k<false, false, false><<<ggrid(MC, QD), 256, 0, stream>>>(
        qin, QD, Wq, QD, q, QD, nullptr, nullptr, 0, QD, QD);
    // t_h = q_h @ WkT0_h   (N=444, K=136)
    for (int hh = 0; hh < 2; ++hh)
      gemm_k<false, false, false><<<ggrid(MC, KD), 256, 0, stream>>>(
          q + hh * HD, QD, wkT + (size_t)hh * HD * KD, KD,
          t + hh * KD, 2 * KD, nullptr, nullptr, 0, KD, HD);
    attn_core<0><<<MC, 320, 0, stream>>>(memories, node_raw, edge_raw, nullptr,
                                         t_node, t_n1, t_n2, time_w, time_b,
                                         n1_ids, n1_eids, n2_ids, n2_eids, off, t);
    // out_h = z_h @ Wv0_h  (N=136, K=444) -> reuse q buffer
    for (int hh = 0; hh < 2; ++hh)
      gemm_k<false, false, false><<<ggrid(MC, HD), 256, 0, stream>>>(
          t + hh * KD, 2 * KD, Wv + hh * HD, QD,
          q + hh * HD, QD, nullptr, nullptr, 0, HD, KD);
    // x = out @ Wo0 + bo0 + qin   (in-place into qin)
    gemm_k<true, true, false><<<ggrid(MC, QD), 256, 0, stream>>>(
        q, QD, Wo, QD, qin, QD, bo, qin, QD, QD, QD);
    ln_cat<0><<<MC, 320, 0, stream>>>(qin, ln_g, ln_b, memories, node_raw,
                                      node_ids, n1_ids, off, cat);
    gemm_k<true, false, true><<<ggrid(MC, DN), 256, 0, stream>>>(
        cat, QD + DN, m_w1, DN, h, DN, m_b1, nullptr, 0, DN, QD + DN);
    gemm_k<true, false, false><<<ggrid(MC, DN), 256, 0, stream>>>(
        h, DN, m_w2, DN, conv1 + (size_t)off * DN, DN, m_b2, nullptr, 0, DN, DN);
  }

  // ---------- layer 2 (M = 1024), weight slice [1] ----------
  build_qin<1><<<Bq, 320, 0, stream>>>(memories, node_raw, conv1, time_b,
                                       node_ids, n1_ids, 0, qin);
  gemm_k<false, false, false><<<ggrid(Bq, QD), 256, 0, stream>>>(
      qin, QD, Wq + QD * QD, QD, q, QD, nullptr, nullptr, 0, QD, QD);
  for (int hh = 0; hh < 2; ++hh)
    gemm_k<false, false, false><<<ggrid(Bq, KD), 256, 0, stream>>>(
        q + hh * HD, QD, wkT + (size_t)QD * KD + (size_t)hh * HD * KD, KD,
        t + hh * KD, 2 * KD, nullptr, nullptr, 0, KD, HD);
  attn_core<1><<<Bq, 320, 0, stream>>>(memories, node_raw, edge_raw, conv1,
                                       t_node, t_n1, t_n2, time_w, time_b,
                                       n1_ids, n1_eids, n2_ids, n2_eids, 0, t);
  for (int hh = 0; hh < 2; ++hh)
    gemm_k<false, false, false><<<ggrid(Bq, HD), 256, 0, stream>>>(
        t + hh * KD, 2 * KD, Wv + (size_t)KD * QD + hh * HD, QD,
        q + hh * HD, QD, nullptr, nullptr, 0, HD, KD);
  gemm_k<true, true, false><<<ggrid(Bq, QD), 256, 0, stream>>>(
      q, QD, Wo + QD * QD, QD, qin, QD, bo + QD, qin, QD, QD, QD);
  ln_cat<1><<<Bq, 320, 0, stream>>>(qin, ln_g + QD, ln_b + QD, memories, node_raw,
                                    node_ids, n1_ids, 0, cat);
  gemm_k<true, false, true><<<ggrid(Bq, DN), 256, 0, stream>>>(
      cat, QD + DN, m_w1 + (QD + DN) * DN, DN, h, DN, m_b1 + DN, nullptr, 0, DN, QD + DN);
  gemm_k<true, false, false><<<ggrid(Bq, DN), 256, 0, stream>>>(
      h, DN, m_w2 + DN * DN, DN, (float*)d_out, DN, m_b2 + DN, nullptr, 0, DN, DN);
}